// Round 7
// baseline (374.324 us; speedup 1.0000x reference)
//
#include <hip/hip_runtime.h>
#include <hip/hip_bf16.h>

#define N_NODES 20000
#define N_EDGES 320000
#define NEG_SLOPE 0.2f

// ---------------- CSR build (by dst) ----------------
__global__ void hist_kernel(const int* __restrict__ dst, int* __restrict__ deg) {
    int e = blockIdx.x * blockDim.x + threadIdx.x;
    if (e < N_EDGES) atomicAdd(&deg[dst[e]], 1);
}

__global__ __launch_bounds__(1024) void scan_kernel(const int* __restrict__ deg,
                                                    int* __restrict__ offsets,
                                                    int* __restrict__ pos) {
    __shared__ int sums[1024];
    const int CH = (N_NODES + 1023) / 1024;  // 20
    int t = threadIdx.x;
    int beg = t * CH;
    int end = min(beg + CH, N_NODES);
    int loc[20];
    int s = 0;
    for (int i = beg; i < end; ++i) { loc[i - beg] = s; s += deg[i]; }
    sums[t] = s;
    __syncthreads();
    for (int st = 1; st < 1024; st <<= 1) {
        int v = (t >= st) ? sums[t - st] : 0;
        __syncthreads();
        sums[t] += v;
        __syncthreads();
    }
    int excl = (t == 0) ? 0 : sums[t - 1];
    for (int i = beg; i < end; ++i) {
        int o = excl + loc[i - beg];
        offsets[i] = o;
        pos[i] = o;
    }
    if (t == 1023) offsets[N_NODES] = sums[1023];
}

__global__ void scatter_kernel(const int* __restrict__ src, const int* __restrict__ dst,
                               int* __restrict__ pos, int* __restrict__ elist) {
    int e = blockIdx.x * blockDim.x + threadIdx.x;
    if (e < N_EDGES) {
        int p = atomicAdd(&pos[dst[e]], 1);
        elist[p] = src[e];
    }
}

// ------------- GEMM1: h1[N,384] = X[N,128] @ W1[128,384]; el1/er1[N,3] -------------
__global__ __launch_bounds__(384) void gemm1_kernel(const float* __restrict__ X,
                                                    const float* __restrict__ W,
                                                    const float* __restrict__ al,
                                                    const float* __restrict__ ar,
                                                    float* __restrict__ H1,
                                                    float* __restrict__ EL,
                                                    float* __restrict__ ER) {
    __shared__ float xs[8][128];
    __shared__ float wsum[8][6][2];
    int col = threadIdx.x;     // 0..383
    int head = col >> 7;
    int f = col & 127;
    int row0 = blockIdx.x * 8;   // grid exact: 2500*8 = 20000
    for (int i = col; i < 8 * 128; i += 384) {
        int r = i >> 7, k = i & 127;
        xs[r][k] = X[(size_t)(row0 + r) * 128 + k];
    }
    __syncthreads();
    float acc[8];
#pragma unroll
    for (int r = 0; r < 8; ++r) acc[r] = 0.f;
    for (int k = 0; k < 128; k += 4) {
        float w0 = W[(size_t)(k + 0) * 384 + col];
        float w1 = W[(size_t)(k + 1) * 384 + col];
        float w2 = W[(size_t)(k + 2) * 384 + col];
        float w3 = W[(size_t)(k + 3) * 384 + col];
#pragma unroll
        for (int r = 0; r < 8; ++r) {
            float4 x = *(const float4*)&xs[r][k];
            acc[r] += x.x * w0 + x.y * w1 + x.z * w2 + x.w * w3;
        }
    }
    float alv = al[head * 128 + f];
    float arv = ar[head * 128 + f];
    int wave = col >> 6;
    int lane = col & 63;
#pragma unroll
    for (int r = 0; r < 8; ++r) {
        H1[(size_t)(row0 + r) * 384 + col] = acc[r];
        float vl = acc[r] * alv;
        float vr = acc[r] * arv;
#pragma unroll
        for (int s = 32; s > 0; s >>= 1) {
            vl += __shfl_down(vl, s);
            vr += __shfl_down(vr, s);
        }
        if (lane == 0) { wsum[r][wave][0] = vl; wsum[r][wave][1] = vr; }
    }
    __syncthreads();
    if (col < 24) {
        int r = col / 3, h = col % 3;
        int gr = row0 + r;
        EL[gr * 3 + h] = wsum[r][2 * h][0] + wsum[r][2 * h + 1][0];
        ER[gr * 3 + h] = wsum[r][2 * h][1] + wsum[r][2 * h + 1][1];
    }
}

// ------------- GEMM2: h2[N,128] = X2[N,384] @ W2[384,128]; el2/er2[N] -------------
__global__ __launch_bounds__(128) void gemm2_kernel(const float* __restrict__ X2,
                                                    const float* __restrict__ W,
                                                    const float* __restrict__ al,
                                                    const float* __restrict__ ar,
                                                    float* __restrict__ H2,
                                                    float* __restrict__ EL,
                                                    float* __restrict__ ER) {
    __shared__ float xs[8][384];
    __shared__ float wsum[8][2][2];
    int col = threadIdx.x;  // 0..127
    int row0 = blockIdx.x * 8;
    for (int i = col; i < 8 * 384; i += 128) {
        int r = i / 384, k = i % 384;
        xs[r][k] = X2[(size_t)(row0 + r) * 384 + k];
    }
    __syncthreads();
    float acc[8];
#pragma unroll
    for (int r = 0; r < 8; ++r) acc[r] = 0.f;
    for (int k = 0; k < 384; k += 4) {
        float w0 = W[(size_t)(k + 0) * 128 + col];
        float w1 = W[(size_t)(k + 1) * 128 + col];
        float w2 = W[(size_t)(k + 2) * 128 + col];
        float w3 = W[(size_t)(k + 3) * 128 + col];
#pragma unroll
        for (int r = 0; r < 8; ++r) {
            float4 x = *(const float4*)&xs[r][k];
            acc[r] += x.x * w0 + x.y * w1 + x.z * w2 + x.w * w3;
        }
    }
    float alv = al[col], arv = ar[col];
    int wave = col >> 6, lane = col & 63;
#pragma unroll
    for (int r = 0; r < 8; ++r) {
        H2[(size_t)(row0 + r) * 128 + col] = acc[r];
        float vl = acc[r] * alv, vr = acc[r] * arv;
#pragma unroll
        for (int s = 32; s > 0; s >>= 1) {
            vl += __shfl_down(vl, s);
            vr += __shfl_down(vr, s);
        }
        if (lane == 0) { wsum[r][wave][0] = vl; wsum[r][wave][1] = vr; }
    }
    __syncthreads();
    if (col < 8) {
        int gr = row0 + col;
        EL[gr] = wsum[col][0][0] + wsum[col][1][0];
        ER[gr] = wsum[col][0][1] + wsum[col][1][1];
    }
}

// ------------- Layer-1 fused edge-softmax + aggregate (per dst node) -------------
__global__ __launch_bounds__(128) void agg1_kernel(const float* __restrict__ H1,
                                                   const float* __restrict__ EL,
                                                   const float* __restrict__ ER,
                                                   const int* __restrict__ offsets,
                                                   const int* __restrict__ elist,
                                                   const float* __restrict__ bias,
                                                   float* __restrict__ OUT) {
    __shared__ int s_src[128];
    __shared__ float s_sc[3][128];
    __shared__ float s_w[3][128];
    int n = blockIdx.x;
    int t = threadIdx.x;  // feature lane
    int o0 = offsets[n], o1 = offsets[n + 1];
    int deg = o1 - o0;
    float er0 = ER[n * 3 + 0], er1v = ER[n * 3 + 1], er2v = ER[n * 3 + 2];
    float m0 = -1e30f, m1 = -1e30f, m2 = -1e30f;
    float l0 = 0.f, l1 = 0.f, l2 = 0.f;
    float a0 = 0.f, a1 = 0.f, a2 = 0.f;
    for (int base = 0; base < deg; base += 128) {
        int cnt = min(128, deg - base);
        if (t < cnt) {
            int s = elist[o0 + base + t];
            s_src[t] = s;
            float e0 = EL[s * 3 + 0] + er0;
            float e1 = EL[s * 3 + 1] + er1v;
            float e2 = EL[s * 3 + 2] + er2v;
            s_sc[0][t] = e0 > 0.f ? e0 : NEG_SLOPE * e0;
            s_sc[1][t] = e1 > 0.f ? e1 : NEG_SLOPE * e1;
            s_sc[2][t] = e2 > 0.f ? e2 : NEG_SLOPE * e2;
        }
        __syncthreads();
        float nm0 = m0, nm1 = m1, nm2 = m2;
        for (int i = 0; i < cnt; ++i) {
            nm0 = fmaxf(nm0, s_sc[0][i]);
            nm1 = fmaxf(nm1, s_sc[1][i]);
            nm2 = fmaxf(nm2, s_sc[2][i]);
        }
        float f0 = __expf(m0 - nm0), f1 = __expf(m1 - nm1), f2 = __expf(m2 - nm2);
        a0 *= f0; a1 *= f1; a2 *= f2;
        l0 *= f0; l1 *= f1; l2 *= f2;
        m0 = nm0; m1 = nm1; m2 = nm2;
        // one exp per edge per head (was: recomputed by all 128 threads)
        if (t < cnt) {
            s_w[0][t] = __expf(s_sc[0][t] - m0);
            s_w[1][t] = __expf(s_sc[1][t] - m1);
            s_w[2][t] = __expf(s_sc[2][t] - m2);
        }
        __syncthreads();
        for (int i = 0; i < cnt; ++i) {
            float w0 = s_w[0][i], w1 = s_w[1][i], w2 = s_w[2][i];
            l0 += w0; l1 += w1; l2 += w2;
            const float* hp = H1 + (size_t)s_src[i] * 384;
            a0 += w0 * hp[t];
            a1 += w1 * hp[128 + t];
            a2 += w2 * hp[256 + t];
        }
        __syncthreads();
    }
    OUT[(size_t)n * 384 + t]       = a0 / l0 + bias[t];
    OUT[(size_t)n * 384 + 128 + t] = a1 / l1 + bias[128 + t];
    OUT[(size_t)n * 384 + 256 + t] = a2 / l2 + bias[256 + t];
}

// ------------- Layer-2 fused edge-softmax + aggregate -------------
__global__ __launch_bounds__(128) void agg2_kernel(const float* __restrict__ H2,
                                                   const float* __restrict__ EL,
                                                   const float* __restrict__ ER,
                                                   const int* __restrict__ offsets,
                                                   const int* __restrict__ elist,
                                                   const float* __restrict__ bias,
                                                   float* __restrict__ OUT) {
    __shared__ int s_src[128];
    __shared__ float s_sc[128];
    __shared__ float s_w[128];
    int n = blockIdx.x;
    int t = threadIdx.x;
    int o0 = offsets[n], o1 = offsets[n + 1];
    int deg = o1 - o0;
    float ern = ER[n];
    float m = -1e30f, l = 0.f, a = 0.f;
    for (int base = 0; base < deg; base += 128) {
        int cnt = min(128, deg - base);
        if (t < cnt) {
            int s = elist[o0 + base + t];
            s_src[t] = s;
            float e = EL[s] + ern;
            s_sc[t] = e > 0.f ? e : NEG_SLOPE * e;
        }
        __syncthreads();
        float nm = m;
        for (int i = 0; i < cnt; ++i) nm = fmaxf(nm, s_sc[i]);
        float fct = __expf(m - nm);
        a *= fct; l *= fct; m = nm;
        if (t < cnt) s_w[t] = __expf(s_sc[t] - m);
        __syncthreads();
        for (int i = 0; i < cnt; ++i) {
            float w = s_w[i];
            l += w;
            a += w * H2[(size_t)s_src[i] * 128 + t];
        }
        __syncthreads();
    }
    OUT[(size_t)n * 128 + t] = a / l + bias[t];
}

extern "C" void kernel_launch(void* const* d_in, const int* in_sizes, int n_in,
                              void* d_out, int out_size, void* d_ws, size_t ws_size,
                              hipStream_t stream) {
    const float* feats = (const float*)d_in[0];
    const float* W1    = (const float*)d_in[1];
    const float* al1   = (const float*)d_in[2];
    const float* ar1   = (const float*)d_in[3];
    const float* b1    = (const float*)d_in[4];
    const float* W2    = (const float*)d_in[5];
    const float* al2   = (const float*)d_in[6];
    const float* ar2   = (const float*)d_in[7];
    const float* b2    = (const float*)d_in[8];
    const int* src     = (const int*)d_in[9];
    const int* dst     = (const int*)d_in[10];
    float* out = (float*)d_out;

    char* ws = (char*)d_ws;
    size_t off = 0;
    auto alloc = [&](size_t bytes) {
        void* p = ws + off;
        off += (bytes + 255) & ~(size_t)255;
        return p;
    };
    float* h1  = (float*)alloc((size_t)N_NODES * 384 * 4);  // also reused as h2
    float* x2  = (float*)alloc((size_t)N_NODES * 384 * 4);
    float* el1 = (float*)alloc((size_t)N_NODES * 3 * 4);
    float* er1 = (float*)alloc((size_t)N_NODES * 3 * 4);
    float* el2 = (float*)alloc((size_t)N_NODES * 4);
    float* er2 = (float*)alloc((size_t)N_NODES * 4);
    int* deg     = (int*)alloc((size_t)N_NODES * 4);
    int* offsets = (int*)alloc((size_t)(N_NODES + 1) * 4);
    int* pos     = (int*)alloc((size_t)N_NODES * 4);
    int* elist   = (int*)alloc((size_t)N_EDGES * 4);
    float* h2 = h1;  // h1 dead after agg1; reuse for h2

    hipMemsetAsync(deg, 0, (size_t)N_NODES * 4, stream);
    hist_kernel<<<(N_EDGES + 255) / 256, 256, 0, stream>>>(dst, deg);
    scan_kernel<<<1, 1024, 0, stream>>>(deg, offsets, pos);
    scatter_kernel<<<(N_EDGES + 255) / 256, 256, 0, stream>>>(src, dst, pos, elist);

    gemm1_kernel<<<N_NODES / 8, 384, 0, stream>>>(feats, W1, al1, ar1, h1, el1, er1);
    agg1_kernel<<<N_NODES, 128, 0, stream>>>(h1, el1, er1, offsets, elist, b1, x2);
    gemm2_kernel<<<N_NODES / 8, 128, 0, stream>>>(x2, W2, al2, ar2, h2, el2, er2);
    agg2_kernel<<<N_NODES, 128, 0, stream>>>(h2, el2, er2, offsets, elist, b2, out);
}

// Round 9
// 321.336 us; speedup vs baseline: 1.1649x; 1.1649x over previous
//
#include <hip/hip_runtime.h>
#include <hip/hip_bf16.h>

#define N_NODES 20000
#define N_EDGES 320000
#define NEG_SLOPE 0.2f

// ---------------- CSR build (by dst) ----------------
__global__ void hist_kernel(const int* __restrict__ dst, int* __restrict__ deg) {
    int e = blockIdx.x * blockDim.x + threadIdx.x;
    if (e < N_EDGES) atomicAdd(&deg[dst[e]], 1);
}

__global__ __launch_bounds__(1024) void scan_kernel(const int* __restrict__ deg,
                                                    int* __restrict__ offsets,
                                                    int* __restrict__ pos) {
    __shared__ int sums[1024];
    const int CH = (N_NODES + 1023) / 1024;  // 20
    int t = threadIdx.x;
    int beg = t * CH;
    int end = min(beg + CH, N_NODES);
    int loc[20];
    int s = 0;
    for (int i = beg; i < end; ++i) { loc[i - beg] = s; s += deg[i]; }
    sums[t] = s;
    __syncthreads();
    for (int st = 1; st < 1024; st <<= 1) {
        int v = (t >= st) ? sums[t - st] : 0;
        __syncthreads();
        sums[t] += v;
        __syncthreads();
    }
    int excl = (t == 0) ? 0 : sums[t - 1];
    for (int i = beg; i < end; ++i) {
        int o = excl + loc[i - beg];
        offsets[i] = o;
        pos[i] = o;
    }
    if (t == 1023) offsets[N_NODES] = sums[1023];
}

__global__ void scatter_kernel(const int* __restrict__ src, const int* __restrict__ dst,
                               int* __restrict__ pos, int* __restrict__ elist) {
    int e = blockIdx.x * blockDim.x + threadIdx.x;
    if (e < N_EDGES) {
        int p = atomicAdd(&pos[dst[e]], 1);
        elist[p] = src[e];
    }
}

// ------------- GEMM1: h1[N,384] = X[N,128] @ W1[128,384]; el1/er1[N,3] -------------
// 32-row x 128-col tile per block (col tile == one head), 256 threads,
// 4x4 micro-tile per thread. grid = (20000/32, 3).
__global__ __launch_bounds__(256) void gemm1_kernel(const float* __restrict__ X,
                                                    const float* __restrict__ W,
                                                    const float* __restrict__ al,
                                                    const float* __restrict__ ar,
                                                    float* __restrict__ H1,
                                                    float* __restrict__ EL,
                                                    float* __restrict__ ER) {
    __shared__ float xsT[128][36];  // [k][m], pad 36: 16B-aligned rows, conflict-free
    int tid = threadIdx.x;
    int tm = tid >> 5;        // 0..7  -> rows tm*4..tm*4+3
    int tn = tid & 31;        // 0..31 -> cols tn*4..tn*4+3
    int row0 = blockIdx.x * 32;
    int head = blockIdx.y;    // 0..2
    int n0 = head * 128;

    // stage X[row0..row0+31][0..127] transposed into xsT[k][m]
#pragma unroll
    for (int j = 0; j < 4; ++j) {
        int idx = tid + j * 256;
        int m = idx >> 5, k4 = idx & 31;
        float4 v = *(const float4*)&X[(size_t)(row0 + m) * 128 + k4 * 4];
        xsT[k4 * 4 + 0][m] = v.x;
        xsT[k4 * 4 + 1][m] = v.y;
        xsT[k4 * 4 + 2][m] = v.z;
        xsT[k4 * 4 + 3][m] = v.w;
    }
    __syncthreads();

    float acc[4][4] = {};
    const float* Wp = W + n0 + tn * 4;
#pragma unroll 4
    for (int k = 0; k < 128; ++k) {
        float4 w = *(const float4*)&Wp[(size_t)k * 384];
        float4 x = *(const float4*)&xsT[k][tm * 4];
        float xv[4] = {x.x, x.y, x.z, x.w};
        float wv[4] = {w.x, w.y, w.z, w.w};
#pragma unroll
        for (int r = 0; r < 4; ++r)
#pragma unroll
            for (int c = 0; c < 4; ++c) acc[r][c] = fmaf(xv[r], wv[c], acc[r][c]);
    }

    float4 av = *(const float4*)&al[n0 + tn * 4];
    float4 rv = *(const float4*)&ar[n0 + tn * 4];
    float avv[4] = {av.x, av.y, av.z, av.w};
    float rvv[4] = {rv.x, rv.y, rv.z, rv.w};
#pragma unroll
    for (int r = 0; r < 4; ++r) {
        int row = row0 + tm * 4 + r;
        float4 o = make_float4(acc[r][0], acc[r][1], acc[r][2], acc[r][3]);
        *(float4*)&H1[(size_t)row * 384 + n0 + tn * 4] = o;
        float vl = acc[r][0] * avv[0] + acc[r][1] * avv[1] + acc[r][2] * avv[2] + acc[r][3] * avv[3];
        float vr = acc[r][0] * rvv[0] + acc[r][1] * rvv[1] + acc[r][2] * rvv[2] + acc[r][3] * rvv[3];
#pragma unroll
        for (int s = 16; s > 0; s >>= 1) {
            vl += __shfl_down(vl, s, 32);
            vr += __shfl_down(vr, s, 32);
        }
        if (tn == 0) {
            EL[row * 3 + head] = vl;
            ER[row * 3 + head] = vr;
        }
    }
}

// ------------- GEMM2: h2[N,128] = X2[N,384] @ W2[384,128]; el2/er2[N] -------------
// 32-row x 128-col tile, K staged in 3 chunks of 128. grid = (20000/32, 1).
__global__ __launch_bounds__(256) void gemm2_kernel(const float* __restrict__ X2,
                                                    const float* __restrict__ W,
                                                    const float* __restrict__ al,
                                                    const float* __restrict__ ar,
                                                    float* __restrict__ H2,
                                                    float* __restrict__ EL,
                                                    float* __restrict__ ER) {
    __shared__ float xsT[128][36];
    int tid = threadIdx.x;
    int tm = tid >> 5;
    int tn = tid & 31;
    int row0 = blockIdx.x * 32;

    float acc[4][4] = {};
    for (int c = 0; c < 3; ++c) {
#pragma unroll
        for (int j = 0; j < 4; ++j) {
            int idx = tid + j * 256;
            int m = idx >> 5, k4 = idx & 31;
            float4 v = *(const float4*)&X2[(size_t)(row0 + m) * 384 + c * 128 + k4 * 4];
            xsT[k4 * 4 + 0][m] = v.x;
            xsT[k4 * 4 + 1][m] = v.y;
            xsT[k4 * 4 + 2][m] = v.z;
            xsT[k4 * 4 + 3][m] = v.w;
        }
        __syncthreads();
        const float* Wp = W + (size_t)c * 128 * 128 + tn * 4;
#pragma unroll 4
        for (int k = 0; k < 128; ++k) {
            float4 w = *(const float4*)&Wp[(size_t)k * 128];
            float4 x = *(const float4*)&xsT[k][tm * 4];
            float xv[4] = {x.x, x.y, x.z, x.w};
            float wv[4] = {w.x, w.y, w.z, w.w};
#pragma unroll
            for (int r = 0; r < 4; ++r)
#pragma unroll
                for (int cc = 0; cc < 4; ++cc) acc[r][cc] = fmaf(xv[r], wv[cc], acc[r][cc]);
        }
        __syncthreads();
    }

    float4 av = *(const float4*)&al[tn * 4];
    float4 rv = *(const float4*)&ar[tn * 4];
    float avv[4] = {av.x, av.y, av.z, av.w};
    float rvv[4] = {rv.x, rv.y, rv.z, rv.w};
#pragma unroll
    for (int r = 0; r < 4; ++r) {
        int row = row0 + tm * 4 + r;
        float4 o = make_float4(acc[r][0], acc[r][1], acc[r][2], acc[r][3]);
        *(float4*)&H2[(size_t)row * 128 + tn * 4] = o;
        float vl = acc[r][0] * avv[0] + acc[r][1] * avv[1] + acc[r][2] * avv[2] + acc[r][3] * avv[3];
        float vr = acc[r][0] * rvv[0] + acc[r][1] * rvv[1] + acc[r][2] * rvv[2] + acc[r][3] * rvv[3];
#pragma unroll
        for (int s = 16; s > 0; s >>= 1) {
            vl += __shfl_down(vl, s, 32);
            vr += __shfl_down(vr, s, 32);
        }
        if (tn == 0) {
            EL[row] = vl;
            ER[row] = vr;
        }
    }
}

// ------------- Layer-1 fused edge-softmax + aggregate (per dst node) -------------
__global__ __launch_bounds__(128) void agg1_kernel(const float* __restrict__ H1,
                                                   const float* __restrict__ EL,
                                                   const float* __restrict__ ER,
                                                   const int* __restrict__ offsets,
                                                   const int* __restrict__ elist,
                                                   const float* __restrict__ bias,
                                                   float* __restrict__ OUT) {
    __shared__ int s_src[128];
    __shared__ float s_sc[3][128];
    __shared__ float s_w[3][128];
    int n = blockIdx.x;
    int t = threadIdx.x;  // feature lane
    int o0 = offsets[n], o1 = offsets[n + 1];
    int deg = o1 - o0;
    float er0 = ER[n * 3 + 0], er1v = ER[n * 3 + 1], er2v = ER[n * 3 + 2];
    float m0 = -1e30f, m1 = -1e30f, m2 = -1e30f;
    float l0 = 0.f, l1 = 0.f, l2 = 0.f;
    float a0 = 0.f, a1 = 0.f, a2 = 0.f;
    for (int base = 0; base < deg; base += 128) {
        int cnt = min(128, deg - base);
        if (t < cnt) {
            int s = elist[o0 + base + t];
            s_src[t] = s;
            float e0 = EL[s * 3 + 0] + er0;
            float e1 = EL[s * 3 + 1] + er1v;
            float e2 = EL[s * 3 + 2] + er2v;
            s_sc[0][t] = e0 > 0.f ? e0 : NEG_SLOPE * e0;
            s_sc[1][t] = e1 > 0.f ? e1 : NEG_SLOPE * e1;
            s_sc[2][t] = e2 > 0.f ? e2 : NEG_SLOPE * e2;
        }
        __syncthreads();
        float nm0 = m0, nm1 = m1, nm2 = m2;
        for (int i = 0; i < cnt; ++i) {
            nm0 = fmaxf(nm0, s_sc[0][i]);
            nm1 = fmaxf(nm1, s_sc[1][i]);
            nm2 = fmaxf(nm2, s_sc[2][i]);
        }
        float f0 = __expf(m0 - nm0), f1 = __expf(m1 - nm1), f2 = __expf(m2 - nm2);
        a0 *= f0; a1 *= f1; a2 *= f2;
        l0 *= f0; l1 *= f1; l2 *= f2;
        m0 = nm0; m1 = nm1; m2 = nm2;
        // one exp per edge per head (was: recomputed by all 128 threads)
        if (t < cnt) {
            s_w[0][t] = __expf(s_sc[0][t] - m0);
            s_w[1][t] = __expf(s_sc[1][t] - m1);
            s_w[2][t] = __expf(s_sc[2][t] - m2);
        }
        __syncthreads();
        for (int i = 0; i < cnt; ++i) {
            float w0 = s_w[0][i], w1 = s_w[1][i], w2 = s_w[2][i];
            l0 += w0; l1 += w1; l2 += w2;
            const float* hp = H1 + (size_t)s_src[i] * 384;
            a0 += w0 * hp[t];
            a1 += w1 * hp[128 + t];
            a2 += w2 * hp[256 + t];
        }
        __syncthreads();
    }
    OUT[(size_t)n * 384 + t]       = a0 / l0 + bias[t];
    OUT[(size_t)n * 384 + 128 + t] = a1 / l1 + bias[128 + t];
    OUT[(size_t)n * 384 + 256 + t] = a2 / l2 + bias[256 + t];
}

// ------------- Layer-2 fused edge-softmax + aggregate -------------
__global__ __launch_bounds__(128) void agg2_kernel(const float* __restrict__ H2,
                                                   const float* __restrict__ EL,
                                                   const float* __restrict__ ER,
                                                   const int* __restrict__ offsets,
                                                   const int* __restrict__ elist,
                                                   const float* __restrict__ bias,
                                                   float* __restrict__ OUT) {
    __shared__ int s_src[128];
    __shared__ float s_sc[128];
    __shared__ float s_w[128];
    int n = blockIdx.x;
    int t = threadIdx.x;
    int o0 = offsets[n], o1 = offsets[n + 1];
    int deg = o1 - o0;
    float ern = ER[n];
    float m = -1e30f, l = 0.f, a = 0.f;
    for (int base = 0; base < deg; base += 128) {
        int cnt = min(128, deg - base);
        if (t < cnt) {
            int s = elist[o0 + base + t];
            s_src[t] = s;
            float e = EL[s] + ern;
            s_sc[t] = e > 0.f ? e : NEG_SLOPE * e;
        }
        __syncthreads();
        float nm = m;
        for (int i = 0; i < cnt; ++i) nm = fmaxf(nm, s_sc[i]);
        float fct = __expf(m - nm);
        a *= fct; l *= fct; m = nm;
        if (t < cnt) s_w[t] = __expf(s_sc[t] - m);
        __syncthreads();
        for (int i = 0; i < cnt; ++i) {
            float w = s_w[i];
            l += w;
            a += w * H2[(size_t)s_src[i] * 128 + t];
        }
        __syncthreads();
    }
    OUT[(size_t)n * 128 + t] = a / l + bias[t];
}

extern "C" void kernel_launch(void* const* d_in, const int* in_sizes, int n_in,
                              void* d_out, int out_size, void* d_ws, size_t ws_size,
                              hipStream_t stream) {
    const float* feats = (const float*)d_in[0];
    const float* W1    = (const float*)d_in[1];
    const float* al1   = (const float*)d_in[2];
    const float* ar1   = (const float*)d_in[3];
    const float* b1    = (const float*)d_in[4];
    const float* W2    = (const float*)d_in[5];
    const float* al2   = (const float*)d_in[6];
    const float* ar2   = (const float*)d_in[7];
    const float* b2    = (const float*)d_in[8];
    const int* src     = (const int*)d_in[9];
    const int* dst     = (const int*)d_in[10];
    float* out = (float*)d_out;

    char* ws = (char*)d_ws;
    size_t off = 0;
    auto alloc = [&](size_t bytes) {
        void* p = ws + off;
        off += (bytes + 255) & ~(size_t)255;
        return p;
    };
    float* h1  = (float*)alloc((size_t)N_NODES * 384 * 4);  // also reused as h2
    float* x2  = (float*)alloc((size_t)N_NODES * 384 * 4);
    float* el1 = (float*)alloc((size_t)N_NODES * 3 * 4);
    float* er1 = (float*)alloc((size_t)N_NODES * 3 * 4);
    float* el2 = (float*)alloc((size_t)N_NODES * 4);
    float* er2 = (float*)alloc((size_t)N_NODES * 4);
    int* deg     = (int*)alloc((size_t)N_NODES * 4);
    int* offsets = (int*)alloc((size_t)(N_NODES + 1) * 4);
    int* pos     = (int*)alloc((size_t)N_NODES * 4);
    int* elist   = (int*)alloc((size_t)N_EDGES * 4);
    float* h2 = h1;  // h1 dead after agg1; reuse for h2

    hipMemsetAsync(deg, 0, (size_t)N_NODES * 4, stream);
    hist_kernel<<<(N_EDGES + 255) / 256, 256, 0, stream>>>(dst, deg);
    scan_kernel<<<1, 1024, 0, stream>>>(deg, offsets, pos);
    scatter_kernel<<<(N_EDGES + 255) / 256, 256, 0, stream>>>(src, dst, pos, elist);

    dim3 g1(N_NODES / 32, 3);
    gemm1_kernel<<<g1, 256, 0, stream>>>(feats, W1, al1, ar1, h1, el1, er1);
    agg1_kernel<<<N_NODES, 128, 0, stream>>>(h1, el1, er1, offsets, elist, b1, x2);
    dim3 g2(N_NODES / 32, 1);
    gemm2_kernel<<<g2, 256, 0, stream>>>(x2, W2, al2, ar2, h2, el2, er2);
    agg2_kernel<<<N_NODES, 128, 0, stream>>>(h2, el2, er2, offsets, elist, b2, out);
}

// Round 10
// 299.254 us; speedup vs baseline: 1.2509x; 1.0738x over previous
//
#include <hip/hip_runtime.h>
#include <hip/hip_bf16.h>

#define N_NODES 20000
#define N_EDGES 320000
#define NEG_SLOPE 0.2f

__device__ __forceinline__ unsigned int bf16pack(float a, float b) {
    unsigned int ua = __float_as_uint(a);
    ua = (ua + 0x7fffu + ((ua >> 16) & 1u)) >> 16;
    unsigned int ub = __float_as_uint(b);
    ub = (ub + 0x7fffu + ((ub >> 16) & 1u)) >> 16;
    return ua | (ub << 16);
}

// ---------------- CSR build (by dst) ----------------
__global__ void hist_kernel(const int* __restrict__ dst, int* __restrict__ deg) {
    int e = blockIdx.x * blockDim.x + threadIdx.x;
    if (e < N_EDGES) atomicAdd(&deg[dst[e]], 1);
}

__global__ __launch_bounds__(1024) void scan_kernel(const int* __restrict__ deg,
                                                    int* __restrict__ offsets,
                                                    int* __restrict__ pos) {
    __shared__ int sums[1024];
    const int CH = (N_NODES + 1023) / 1024;  // 20
    int t = threadIdx.x;
    int beg = t * CH;
    int end = min(beg + CH, N_NODES);
    int loc[20];
    int s = 0;
    for (int i = beg; i < end; ++i) { loc[i - beg] = s; s += deg[i]; }
    sums[t] = s;
    __syncthreads();
    for (int st = 1; st < 1024; st <<= 1) {
        int v = (t >= st) ? sums[t - st] : 0;
        __syncthreads();
        sums[t] += v;
        __syncthreads();
    }
    int excl = (t == 0) ? 0 : sums[t - 1];
    for (int i = beg; i < end; ++i) {
        int o = excl + loc[i - beg];
        offsets[i] = o;
        pos[i] = o;
    }
    if (t == 1023) offsets[N_NODES] = sums[1023];
}

__global__ void scatter_kernel(const int* __restrict__ src, const int* __restrict__ dst,
                               int* __restrict__ pos, int* __restrict__ elist) {
    int e = blockIdx.x * blockDim.x + threadIdx.x;
    if (e < N_EDGES) {
        int p = atomicAdd(&pos[dst[e]], 1);
        elist[p] = src[e];
    }
}

// ------------- GEMM1: h1[N,384] = X[N,128] @ W1[128,384] (bf16-packed out); el1/er1[N,3] -------------
// 32-row x 128-col tile per block (col tile == one head), 256 threads,
// 4x4 micro-tile per thread. grid = (20000/32, 3).
// H1b layout: [node][96] uint2; uint index hd*64+q holds features (2q,2q+1) of head hd.
__global__ __launch_bounds__(256) void gemm1_kernel(const float* __restrict__ X,
                                                    const float* __restrict__ W,
                                                    const float* __restrict__ al,
                                                    const float* __restrict__ ar,
                                                    uint2* __restrict__ H1b,
                                                    float* __restrict__ EL,
                                                    float* __restrict__ ER) {
    __shared__ float xsT[128][36];  // [k][m], pad 36: conflict-free
    int tid = threadIdx.x;
    int tm = tid >> 5;        // 0..7  -> rows tm*4..tm*4+3
    int tn = tid & 31;        // 0..31 -> cols tn*4..tn*4+3
    int row0 = blockIdx.x * 32;
    int head = blockIdx.y;    // 0..2
    int n0 = head * 128;

#pragma unroll
    for (int j = 0; j < 4; ++j) {
        int idx = tid + j * 256;
        int m = idx >> 5, k4 = idx & 31;
        float4 v = *(const float4*)&X[(size_t)(row0 + m) * 128 + k4 * 4];
        xsT[k4 * 4 + 0][m] = v.x;
        xsT[k4 * 4 + 1][m] = v.y;
        xsT[k4 * 4 + 2][m] = v.z;
        xsT[k4 * 4 + 3][m] = v.w;
    }
    __syncthreads();

    float acc[4][4] = {};
    const float* Wp = W + n0 + tn * 4;
#pragma unroll 4
    for (int k = 0; k < 128; ++k) {
        float4 w = *(const float4*)&Wp[(size_t)k * 384];
        float4 x = *(const float4*)&xsT[k][tm * 4];
        float xv[4] = {x.x, x.y, x.z, x.w};
        float wv[4] = {w.x, w.y, w.z, w.w};
#pragma unroll
        for (int r = 0; r < 4; ++r)
#pragma unroll
            for (int c = 0; c < 4; ++c) acc[r][c] = fmaf(xv[r], wv[c], acc[r][c]);
    }

    float4 av = *(const float4*)&al[n0 + tn * 4];
    float4 rv = *(const float4*)&ar[n0 + tn * 4];
    float avv[4] = {av.x, av.y, av.z, av.w};
    float rvv[4] = {rv.x, rv.y, rv.z, rv.w};
#pragma unroll
    for (int r = 0; r < 4; ++r) {
        int row = row0 + tm * 4 + r;
        uint2 pk;
        pk.x = bf16pack(acc[r][0], acc[r][1]);
        pk.y = bf16pack(acc[r][2], acc[r][3]);
        H1b[(size_t)row * 96 + head * 32 + tn] = pk;
        float vl = acc[r][0] * avv[0] + acc[r][1] * avv[1] + acc[r][2] * avv[2] + acc[r][3] * avv[3];
        float vr = acc[r][0] * rvv[0] + acc[r][1] * rvv[1] + acc[r][2] * rvv[2] + acc[r][3] * rvv[3];
#pragma unroll
        for (int s = 16; s > 0; s >>= 1) {
            vl += __shfl_down(vl, s, 32);
            vr += __shfl_down(vr, s, 32);
        }
        if (tn == 0) {
            EL[row * 3 + head] = vl;
            ER[row * 3 + head] = vr;
        }
    }
}

// ------------- GEMM2: h2[N,128] = X2[N,384] @ W2[384,128]; el2/er2[N] -------------
__global__ __launch_bounds__(256) void gemm2_kernel(const float* __restrict__ X2,
                                                    const float* __restrict__ W,
                                                    const float* __restrict__ al,
                                                    const float* __restrict__ ar,
                                                    float* __restrict__ H2,
                                                    float* __restrict__ EL,
                                                    float* __restrict__ ER) {
    __shared__ float xsT[128][36];
    int tid = threadIdx.x;
    int tm = tid >> 5;
    int tn = tid & 31;
    int row0 = blockIdx.x * 32;

    float acc[4][4] = {};
    for (int c = 0; c < 3; ++c) {
#pragma unroll
        for (int j = 0; j < 4; ++j) {
            int idx = tid + j * 256;
            int m = idx >> 5, k4 = idx & 31;
            float4 v = *(const float4*)&X2[(size_t)(row0 + m) * 384 + c * 128 + k4 * 4];
            xsT[k4 * 4 + 0][m] = v.x;
            xsT[k4 * 4 + 1][m] = v.y;
            xsT[k4 * 4 + 2][m] = v.z;
            xsT[k4 * 4 + 3][m] = v.w;
        }
        __syncthreads();
        const float* Wp = W + (size_t)c * 128 * 128 + tn * 4;
#pragma unroll 4
        for (int k = 0; k < 128; ++k) {
            float4 w = *(const float4*)&Wp[(size_t)k * 128];
            float4 x = *(const float4*)&xsT[k][tm * 4];
            float xv[4] = {x.x, x.y, x.z, x.w};
            float wv[4] = {w.x, w.y, w.z, w.w};
#pragma unroll
            for (int r = 0; r < 4; ++r)
#pragma unroll
                for (int cc = 0; cc < 4; ++cc) acc[r][cc] = fmaf(xv[r], wv[cc], acc[r][cc]);
        }
        __syncthreads();
    }

    float4 av = *(const float4*)&al[tn * 4];
    float4 rv = *(const float4*)&ar[tn * 4];
    float avv[4] = {av.x, av.y, av.z, av.w};
    float rvv[4] = {rv.x, rv.y, rv.z, rv.w};
#pragma unroll
    for (int r = 0; r < 4; ++r) {
        int row = row0 + tm * 4 + r;
        float4 o = make_float4(acc[r][0], acc[r][1], acc[r][2], acc[r][3]);
        *(float4*)&H2[(size_t)row * 128 + tn * 4] = o;
        float vl = acc[r][0] * avv[0] + acc[r][1] * avv[1] + acc[r][2] * avv[2] + acc[r][3] * avv[3];
        float vr = acc[r][0] * rvv[0] + acc[r][1] * rvv[1] + acc[r][2] * rvv[2] + acc[r][3] * rvv[3];
#pragma unroll
        for (int s = 16; s > 0; s >>= 1) {
            vl += __shfl_down(vl, s, 32);
            vr += __shfl_down(vr, s, 32);
        }
        if (tn == 0) {
            EL[row] = vl;
            ER[row] = vr;
        }
    }
}

// ------------- Layer-1 fused edge-softmax + aggregate (bf16 gathers) -------------
// 192 threads: wave hd (=t/64) owns head hd; lane q (=t&63) owns feature pair (2q,2q+1).
__global__ __launch_bounds__(192) void agg1_kernel(const unsigned int* __restrict__ H1b,
                                                   const float* __restrict__ EL,
                                                   const float* __restrict__ ER,
                                                   const int* __restrict__ offsets,
                                                   const int* __restrict__ elist,
                                                   const float* __restrict__ bias,
                                                   float* __restrict__ OUT) {
    __shared__ int s_src[128];
    __shared__ float s_sc[3][128];
    __shared__ float s_w[3][128];
    int n = blockIdx.x;
    int t = threadIdx.x;
    int hd = t >> 6;   // 0..2
    int q  = t & 63;   // feature pair
    int o0 = offsets[n], o1 = offsets[n + 1];
    int deg = o1 - o0;
    float er0 = ER[n * 3 + 0], er1v = ER[n * 3 + 1], er2v = ER[n * 3 + 2];
    float m = -1e30f, l = 0.f, alo = 0.f, ahi = 0.f;
    for (int base = 0; base < deg; base += 128) {
        int cnt = min(128, deg - base);
        if (t < cnt) {  // cnt<=128, so only waves 0/1 participate
            int s = elist[o0 + base + t];
            s_src[t] = s;
            float e0 = EL[s * 3 + 0] + er0;
            float e1 = EL[s * 3 + 1] + er1v;
            float e2 = EL[s * 3 + 2] + er2v;
            s_sc[0][t] = e0 > 0.f ? e0 : NEG_SLOPE * e0;
            s_sc[1][t] = e1 > 0.f ? e1 : NEG_SLOPE * e1;
            s_sc[2][t] = e2 > 0.f ? e2 : NEG_SLOPE * e2;
        }
        __syncthreads();
        float nm = m;
        for (int i = 0; i < cnt; ++i) nm = fmaxf(nm, s_sc[hd][i]);
        float f = __expf(m - nm);
        alo *= f; ahi *= f; l *= f;
        m = nm;
        if (q < cnt)      s_w[hd][q]      = __expf(s_sc[hd][q] - m);
        if (q + 64 < cnt) s_w[hd][q + 64] = __expf(s_sc[hd][q + 64] - m);
        __syncthreads();
        for (int i = 0; i < cnt; ++i) {
            float w = s_w[hd][i];
            l += w;
            unsigned int v = H1b[(size_t)s_src[i] * 192 + hd * 64 + q];
            float lo = __uint_as_float(v << 16);
            float hi = __uint_as_float(v & 0xffff0000u);
            alo = fmaf(w, lo, alo);
            ahi = fmaf(w, hi, ahi);
        }
        __syncthreads();
    }
    int fo = n * 384 + hd * 128 + 2 * q;
    OUT[fo]     = alo / l + bias[hd * 128 + 2 * q];
    OUT[fo + 1] = ahi / l + bias[hd * 128 + 2 * q + 1];
}

// ------------- Layer-2 fused edge-softmax + aggregate -------------
__global__ __launch_bounds__(128) void agg2_kernel(const float* __restrict__ H2,
                                                   const float* __restrict__ EL,
                                                   const float* __restrict__ ER,
                                                   const int* __restrict__ offsets,
                                                   const int* __restrict__ elist,
                                                   const float* __restrict__ bias,
                                                   float* __restrict__ OUT) {
    __shared__ int s_src[128];
    __shared__ float s_sc[128];
    __shared__ float s_w[128];
    int n = blockIdx.x;
    int t = threadIdx.x;
    int o0 = offsets[n], o1 = offsets[n + 1];
    int deg = o1 - o0;
    float ern = ER[n];
    float m = -1e30f, l = 0.f, a = 0.f;
    for (int base = 0; base < deg; base += 128) {
        int cnt = min(128, deg - base);
        if (t < cnt) {
            int s = elist[o0 + base + t];
            s_src[t] = s;
            float e = EL[s] + ern;
            s_sc[t] = e > 0.f ? e : NEG_SLOPE * e;
        }
        __syncthreads();
        float nm = m;
        for (int i = 0; i < cnt; ++i) nm = fmaxf(nm, s_sc[i]);
        float fct = __expf(m - nm);
        a *= fct; l *= fct; m = nm;
        if (t < cnt) s_w[t] = __expf(s_sc[t] - m);
        __syncthreads();
        for (int i = 0; i < cnt; ++i) {
            float w = s_w[i];
            l += w;
            a += w * H2[(size_t)s_src[i] * 128 + t];
        }
        __syncthreads();
    }
    OUT[(size_t)n * 128 + t] = a / l + bias[t];
}

extern "C" void kernel_launch(void* const* d_in, const int* in_sizes, int n_in,
                              void* d_out, int out_size, void* d_ws, size_t ws_size,
                              hipStream_t stream) {
    const float* feats = (const float*)d_in[0];
    const float* W1    = (const float*)d_in[1];
    const float* al1   = (const float*)d_in[2];
    const float* ar1   = (const float*)d_in[3];
    const float* b1    = (const float*)d_in[4];
    const float* W2    = (const float*)d_in[5];
    const float* al2   = (const float*)d_in[6];
    const float* ar2   = (const float*)d_in[7];
    const float* b2    = (const float*)d_in[8];
    const int* src     = (const int*)d_in[9];
    const int* dst     = (const int*)d_in[10];
    float* out = (float*)d_out;

    char* ws = (char*)d_ws;
    size_t off = 0;
    auto alloc = [&](size_t bytes) {
        void* p = ws + off;
        off += (bytes + 255) & ~(size_t)255;
        return p;
    };
    unsigned int* h1b = (unsigned int*)alloc((size_t)N_NODES * 192 * 4);  // bf16-packed h1; reused as f32 h2
    float* x2  = (float*)alloc((size_t)N_NODES * 384 * 4);
    float* el1 = (float*)alloc((size_t)N_NODES * 3 * 4);
    float* er1 = (float*)alloc((size_t)N_NODES * 3 * 4);
    float* el2 = (float*)alloc((size_t)N_NODES * 4);
    float* er2 = (float*)alloc((size_t)N_NODES * 4);
    int* deg     = (int*)alloc((size_t)N_NODES * 4);
    int* offsets = (int*)alloc((size_t)(N_NODES + 1) * 4);
    int* pos     = (int*)alloc((size_t)N_NODES * 4);
    int* elist   = (int*)alloc((size_t)N_EDGES * 4);
    float* h2 = (float*)h1b;  // h1b dead after agg1 (15.4MB >= 10.2MB needed)

    hipMemsetAsync(deg, 0, (size_t)N_NODES * 4, stream);
    hist_kernel<<<(N_EDGES + 255) / 256, 256, 0, stream>>>(dst, deg);
    scan_kernel<<<1, 1024, 0, stream>>>(deg, offsets, pos);
    scatter_kernel<<<(N_EDGES + 255) / 256, 256, 0, stream>>>(src, dst, pos, elist);

    dim3 g1(N_NODES / 32, 3);
    gemm1_kernel<<<g1, 256, 0, stream>>>(feats, W1, al1, ar1, (uint2*)h1b, el1, er1);
    agg1_kernel<<<N_NODES, 192, 0, stream>>>(h1b, el1, er1, offsets, elist, b1, x2);
    dim3 g2(N_NODES / 32, 1);
    gemm2_kernel<<<g2, 256, 0, stream>>>(x2, W2, al2, ar2, h2, el2, er2);
    agg2_kernel<<<N_NODES, 128, 0, stream>>>(h2, el2, er2, offsets, elist, b2, out);
}